// Round 1
// baseline (99.477 us; speedup 1.0000x reference)
//
#include <hip/hip_runtime.h>
#include <math.h>

#define NUM_CAM   12   // B*N
#define CAM_PER_B 6
#define IMG_H     128
#define IMG_W     352
#define CH        32
#define BEV       200  // BEV_H == BEV_W
#define TILE_X    8
#define TILE_Y    4
#define TILES_X   (BEV / TILE_X)          // 25
#define TILES_Y   (BEV / TILE_Y)          // 50
#define TILES_PER_B (TILES_X * TILES_Y)   // 1250
#define NWG       (2 * TILES_PER_B)       // 2500
#define PIX_PER_BLOCK 32

typedef float vfloat4 __attribute__((ext_vector_type(4)));

// Compacted per-(pixel) camera entry: bilinear corner products + corner00 offset.
struct __align__(16) Entry {
    float c00, c01, c10, c11;  // wx0*wy0, wx0*wy1, wx1*wy0, wx1*wy1
    int   off;                 // element offset of corner (x0,y0); always valid
    int   pad0, pad1, pad2;    // stride 32B -> ds_read_b128 friendly
};

// One block = 8x4 BEV tile (32 pixels), all within one batch.
// Phase 1: 192 threads (one per (pixel,camera)) compute projection; VALID cams
//   are COMPACTED per pixel into slist[slot][pix] via an LDS atomic counter.
// Phase 2: 8 threads per pixel (float4 of channels each) loop over the wave-max
//   valid count kw in PAIRS: both entries' 8 global_load_dwordx4 issue in one
//   basic block (no divergent branch) before any consumption -> ~1 latency
//   exposure instead of up to 6 serialized vmcnt(0) waits. Lanes past their own
//   count get a cndmask'd dummy (off=0, weights=0) -> contributes exactly 0.
// CORRECTNESS NOTES (hard-won, preserved from the verified kernel):
//  - px,py use true IEEE division (rcp-mul flips floor/valid decisions).
//  - invalid cams contribute exactly 0 (reference's clipped-weight cancellation),
//    so best starts at 0 when k<6 and at -INF when all 6 cams are valid.
//  - max over finite floats is order-independent -> compaction order (atomic
//    slot order) does not change the result.
//  - linspace in f64 then cast to f32, P=K@RT k-ordered f32, per-contribution
//    summation order ((t00+t01)+t10)+t11 bitwise identical to reference.
__global__ __launch_bounds__(256, 6) void ipm_kernel(
    const float* __restrict__ imgs,   // (12, 128, 352, 32)
    const float* __restrict__ Ks,     // (12, 4, 4)
    const float* __restrict__ RTs,    // (12, 4, 4)
    float* __restrict__ out)          // (2, 200, 200, 32)
{
    __shared__ Entry slist[CAM_PER_B][PIX_PER_BLOCK];  // 6*32*32B = 6 KiB
    __shared__ int   scnt[PIX_PER_BLOCK];

    const int tid = threadIdx.x;

    // Bijective chunked XCD swizzle (2500 = 8*312 + 4): each XCD gets a
    // contiguous band of BEV tiles -> its private L2 holds one compact
    // image working set instead of a round-robin scatter.
    {
    }
    const int wg  = blockIdx.x;
    const int q   = NWG >> 3;          // 312
    const int r   = NWG & 7;           // 4
    const int xcd = wg & 7;
    const int ix  = wg >> 3;
    const int L   = (xcd < r) ? (xcd * (q + 1) + ix)
                              : (r * (q + 1) + (xcd - r) * q + ix);

    const int b  = L / TILES_PER_B;
    const int t  = L - b * TILES_PER_B;
    const int by = t / TILES_X;
    const int bx = t - by * TILES_X;

    if (tid < PIX_PER_BLOCK) scnt[tid] = 0;
    __syncthreads();

    // ---- Phase 1: one thread per (camera, pixel) ----
    if (tid < CAM_PER_B * PIX_PER_BLOCK) {
        const int cam = tid >> 5;          // 0..5
        const int pix = tid & 31;          // 0..31
        const int gx = bx * TILE_X + (pix & 7);
        const int gy = by * TILE_Y + (pix >> 3);

        // linspace(-50,50,200) in f64 then cast to f32 (matches numpy)
        const double step = 100.0 / 199.0;
        const float xf = (float)(-50.0 + (double)gx * step);
        const float yf = (float)(-50.0 + (double)gy * step);

        const int cg = b * CAM_PER_B + cam;      // global camera id
        const float* K  = Ks  + cg * 16;
        const float* RT = RTs + cg * 16;

        // P = K @ RT, rows 0..2, cols {0,1,3}; k-ordered f32 accumulation
        float P[9];
        #pragma unroll
        for (int rr = 0; rr < 3; ++rr) {
            #pragma unroll
            for (int cc = 0; cc < 3; ++cc) {
                const int col = (cc == 2) ? 3 : cc;
                float acc = 0.0f;
                #pragma unroll
                for (int kk = 0; kk < 4; ++kk)
                    acc += K[rr * 4 + kk] * RT[kk * 4 + col];
                P[rr * 3 + cc] = acc;
            }
        }

        // pc = P @ [yf, xf, 0, 1]; exact IEEE division like the reference
        const float den = (P[6] * yf + P[7] * xf + P[8]) + 1e-7f;
        const float px  = (P[0] * yf + P[1] * xf + P[2]) / den;
        const float py  = (P[3] * yf + P[4] * xf + P[5]) / den;

        const float x0f = floorf(px);
        const float y0f = floorf(py);

        const bool valid = (x0f >= 0.0f) & (x0f <= (float)(IMG_W - 2)) &
                           (y0f >= 0.0f) & (y0f <= (float)(IMG_H - 2));

        if (valid) {
            // Reference weight formulas (in-range: x1 = x0+1 unclipped)
            const float wx1 = px - x0f;
            const float wx0 = (x0f + 1.0f) - px;
            const float wy1 = py - y0f;
            const float wy0 = (y0f + 1.0f) - py;
            const int xi = (int)x0f;
            const int yi = (int)y0f;
            const int off = ((cg * IMG_H + yi) * IMG_W + xi) * CH;

            const int slot = atomicAdd(&scnt[pix], 1);
            float4 cprod;
            cprod.x = wx0 * wy0;   // c00
            cprod.y = wx0 * wy1;   // c01
            cprod.z = wx1 * wy0;   // c10
            cprod.w = wx1 * wy1;   // c11
            *(float4*)&slist[slot][pix] = cprod;   // ds_write_b128
            slist[slot][pix].off = off;
        }
    }
    __syncthreads();

    // ---- Phase 2: 8 threads per pixel, 4 channels each ----
    const int pix = tid >> 3;                 // 0..31
    const int c4  = (tid & 7) * 4;            // channel offset
    const int gx = bx * TILE_X + (pix & 7);
    const int gy = by * TILE_Y + (pix >> 3);

    const int k = scnt[pix];                  // valid cams for this pixel
    int kw = k;                               // wave-uniform max (8 pixel groups)
    kw = max(kw, __shfl_xor(kw, 8));
    kw = max(kw, __shfl_xor(kw, 16));
    kw = max(kw, __shfl_xor(kw, 32));

    const float binit = (k == 6) ? -INFINITY : 0.0f;
    float4 best = make_float4(binit, binit, binit, binit);

    for (int j = 0; j < kw; j += 2) {         // uniform trip count, no divergence
        // entry j (A) and j+1 (B); j+1 <= 5 always (kw<=6, j even)
        float4 cA = *(const float4*)&slist[j][pix];
        int offA  = slist[j][pix].off;
        float4 cB = *(const float4*)&slist[j + 1][pix];
        int offB  = slist[j + 1][pix].off;

        const bool aAct = (j < k);
        const bool bAct = (j + 1 < k);
        if (!aAct) { cA = make_float4(0.f, 0.f, 0.f, 0.f); offA = 0; }
        if (!bAct) { cB = make_float4(0.f, 0.f, 0.f, 0.f); offB = 0; }

        const float* pA = imgs + offA + c4;
        const float* pB = imgs + offB + c4;
        // 8 independent dwordx4 loads, all issued before any consumption
        const float4 a00 = *(const float4*)(pA);
        const float4 a10 = *(const float4*)(pA + CH);
        const float4 a01 = *(const float4*)(pA + IMG_W * CH);
        const float4 a11 = *(const float4*)(pA + IMG_W * CH + CH);
        const float4 e00 = *(const float4*)(pB);
        const float4 e10 = *(const float4*)(pB + CH);
        const float4 e01 = *(const float4*)(pB + IMG_W * CH);
        const float4 e11 = *(const float4*)(pB + IMG_W * CH + CH);

        float4 vA, vB;
        // Reference summation order: ((t00 + t01) + t10) + t11
        vA.x = ((cA.x * a00.x + cA.y * a01.x) + cA.z * a10.x) + cA.w * a11.x;
        vA.y = ((cA.x * a00.y + cA.y * a01.y) + cA.z * a10.y) + cA.w * a11.y;
        vA.z = ((cA.x * a00.z + cA.y * a01.z) + cA.z * a10.z) + cA.w * a11.z;
        vA.w = ((cA.x * a00.w + cA.y * a01.w) + cA.z * a10.w) + cA.w * a11.w;

        vB.x = ((cB.x * e00.x + cB.y * e01.x) + cB.z * e10.x) + cB.w * e11.x;
        vB.y = ((cB.x * e00.y + cB.y * e01.y) + cB.z * e10.y) + cB.w * e11.y;
        vB.z = ((cB.x * e00.z + cB.y * e01.z) + cB.z * e10.z) + cB.w * e11.z;
        vB.w = ((cB.x * e00.w + cB.y * e01.w) + cB.z * e10.w) + cB.w * e11.w;

        best.x = fmaxf(fmaxf(best.x, vA.x), vB.x);
        best.y = fmaxf(fmaxf(best.y, vA.y), vB.y);
        best.z = fmaxf(fmaxf(best.z, vA.z), vB.z);
        best.w = fmaxf(fmaxf(best.w, vA.w), vB.w);
    }

    // Output is write-once; nontemporal keeps image lines resident in L2.
    const size_t o = ((size_t)(b * BEV + gy) * BEV + gx) * CH + c4;
    vfloat4 bv;
    bv.x = best.x; bv.y = best.y; bv.z = best.z; bv.w = best.w;
    __builtin_nontemporal_store(bv, (vfloat4*)(out + o));
}

extern "C" void kernel_launch(void* const* d_in, const int* in_sizes, int n_in,
                              void* d_out, int out_size, void* d_ws, size_t ws_size,
                              hipStream_t stream) {
    const float* images = (const float*)d_in[0];  // (2,6,128,352,32) f32
    const float* Ks     = (const float*)d_in[1];  // (12,4,4) f32
    const float* RTs    = (const float*)d_in[2];  // (12,4,4) f32
    float* out          = (float*)d_out;          // (2,200,200,32) f32

    ipm_kernel<<<NWG, 256, 0, stream>>>(images, Ks, RTs, out);
}